// Round 10
// baseline (297.269 us; speedup 1.0000x reference)
//
#include <hip/hip_runtime.h>
#include <hip/hip_bf16.h>
#include <math.h>

#define N_NODES 50000
#define N_EDGES 600000
#define D_IN    44

// ---------------- CSR build ----------------

__global__ void k_zero(int* p, int n) {
    int i = blockIdx.x * blockDim.x + threadIdx.x;
    if (i < n) p[i] = 0;
}

__global__ void k_count(const int* __restrict__ dst, int* degc, int e) {
    int i = blockIdx.x * blockDim.x + threadIdx.x;
    if (i < e) atomicAdd(&degc[dst[i]], 1);
}

__global__ void k_blocksum(const int* __restrict__ degc, int* __restrict__ bsum, int n) {
    int i = blockIdx.x * 256 + threadIdx.x;
    int v = (i < n) ? degc[i] : 0;
    #pragma unroll
    for (int off = 32; off > 0; off >>= 1) v += __shfl_down(v, off, 64);
    __shared__ int ws[4];
    if ((threadIdx.x & 63) == 0) ws[threadIdx.x >> 6] = v;
    __syncthreads();
    if (threadIdx.x == 0) bsum[blockIdx.x] = ws[0] + ws[1] + ws[2] + ws[3];
}

__global__ void k_scanbsum(int* bsum, int nb) {
    __shared__ int s[256];
    int t = threadIdx.x;
    int v = (t < nb) ? bsum[t] : 0;
    s[t] = v;
    __syncthreads();
    #pragma unroll
    for (int off = 1; off < 256; off <<= 1) {
        int u = (t >= off) ? s[t - off] : 0;
        __syncthreads();
        s[t] += u;
        __syncthreads();
    }
    if (t < nb) bsum[t] = (t == 0) ? 0 : s[t - 1];
}

__global__ void k_rowptr(const int* __restrict__ degc, const int* __restrict__ bsum,
                         int* __restrict__ row_ptr, int* __restrict__ cursor,
                         float* __restrict__ dinv, int n) {
    __shared__ int s[256];
    int i = blockIdx.x * 256 + threadIdx.x;
    int t = threadIdx.x;
    int d = (i < n) ? degc[i] : 0;
    s[t] = d;
    __syncthreads();
    #pragma unroll
    for (int off = 1; off < 256; off <<= 1) {
        int u = (t >= off) ? s[t - off] : 0;
        __syncthreads();
        s[t] += u;
        __syncthreads();
    }
    int ex = s[t] - d + bsum[blockIdx.x];
    if (i < n) {
        row_ptr[i] = ex;
        cursor[i]  = ex;
        dinv[i]    = rsqrtf(1.0f + (float)d);
        if (i == n - 1) row_ptr[n] = ex + d;
    }
}

__global__ void k_fill(const int* __restrict__ src, const int* __restrict__ dst,
                       const float* __restrict__ dinv, int* cursor,
                       int2* __restrict__ csr_ew, int e) {
    int i = blockIdx.x * blockDim.x + threadIdx.x;
    if (i < e) {
        int s = src[i], d = dst[i];
        int p = atomicAdd(&cursor[d], 1);
        csr_ew[p] = make_int2(s, __float_as_int(dinv[s] * dinv[d]));
    }
}

// ---------------- CSR gather-aggregate ----------------
// Exact lane mapping: global lane idx -> (node g, float4-chunk j). Predicated
// 8-deep gather: indices clamped, weights zeroed past row end -> 8 loads in
// flight for every edge group, no serial tail.

template<int W4, bool BIAS_RELU>
__global__ void k_agg(const float* __restrict__ T, const float* __restrict__ dinv,
                      const int* __restrict__ row_ptr, const int2* __restrict__ csr_ew,
                      const float* __restrict__ b, float* __restrict__ O, int n) {
    int idx = blockIdx.x * 256 + threadIdx.x;
    if (idx >= n * W4) return;
    int g = idx / W4;
    int j = idx - g * W4;

    const float4* T4 = (const float4*)T;
    float di = dinv[g];
    float sw = di * di;
    float4 t = T4[(size_t)g * W4 + j];
    float4 acc = make_float4(sw * t.x, sw * t.y, sw * t.z, sw * t.w);

    int lo = row_ptr[g], hi = row_ptr[g + 1];
    for (int k = lo; k < hi; k += 8) {
#define AGG_SLOT(i, ev, tv, wv) \
        int2 ev = csr_ew[min(k + (i), hi - 1)]; \
        float wv = (k + (i) < hi) ? __int_as_float(ev.y) : 0.0f; \
        float4 tv = T4[(size_t)ev.x * W4 + j];
        AGG_SLOT(0, e0, t0, w0)
        AGG_SLOT(1, e1, t1, w1)
        AGG_SLOT(2, e2, t2, w2)
        AGG_SLOT(3, e3, t3, w3)
        AGG_SLOT(4, e4, t4, w4)
        AGG_SLOT(5, e5, t5, w5)
        AGG_SLOT(6, e6, t6, w6)
        AGG_SLOT(7, e7, t7, w7)
#undef AGG_SLOT
        acc.x += w0 * t0.x; acc.y += w0 * t0.y; acc.z += w0 * t0.z; acc.w += w0 * t0.w;
        acc.x += w1 * t1.x; acc.y += w1 * t1.y; acc.z += w1 * t1.z; acc.w += w1 * t1.w;
        acc.x += w2 * t2.x; acc.y += w2 * t2.y; acc.z += w2 * t2.z; acc.w += w2 * t2.w;
        acc.x += w3 * t3.x; acc.y += w3 * t3.y; acc.z += w3 * t3.z; acc.w += w3 * t3.w;
        acc.x += w4 * t4.x; acc.y += w4 * t4.y; acc.z += w4 * t4.z; acc.w += w4 * t4.w;
        acc.x += w5 * t5.x; acc.y += w5 * t5.y; acc.z += w5 * t5.z; acc.w += w5 * t5.w;
        acc.x += w6 * t6.x; acc.y += w6 * t6.y; acc.z += w6 * t6.z; acc.w += w6 * t6.w;
        acc.x += w7 * t7.x; acc.y += w7 * t7.y; acc.z += w7 * t7.z; acc.w += w7 * t7.w;
    }
    if (BIAS_RELU) {
        float4 bv = ((const float4*)b)[j];
        acc.x = fmaxf(acc.x + bv.x, 0.0f);
        acc.y = fmaxf(acc.y + bv.y, 0.0f);
        acc.z = fmaxf(acc.z + bv.z, 0.0f);
        acc.w = fmaxf(acc.w + bv.w, 0.0f);
    }
    ((float4*)O)[(size_t)g * W4 + j] = acc;
}

// ---------------- register-blocked GEMM, W read via uniform (scalar) loads ----------------
// W addresses are wave-uniform (ct0 from blockIdx, k compile-time) ->
// compiler emits s_load into SGPRs; inner loop is pure v_fma. No LDS.

template<int DI, int DO, int CT, bool BIAS_RELU>
__global__ void k_gemm(const float* __restrict__ X, const float* __restrict__ W,
                       const float* __restrict__ b, float* __restrict__ H, int n) {
    const int ct0 = blockIdx.y * CT;
    int node = blockIdx.x * blockDim.x + threadIdx.x;
    if (node >= n) return;

    float acc[CT];
    #pragma unroll
    for (int c = 0; c < CT; ++c) acc[c] = BIAS_RELU ? b[ct0 + c] : 0.0f;

    const float4* xr = (const float4*)(X + (size_t)node * DI);
    const float*  Wb = W + ct0;
    #pragma unroll
    for (int k0 = 0; k0 < DI / 4; ++k0) {
        float4 xv = xr[k0];
        #pragma unroll
        for (int c = 0; c < CT; ++c) acc[c] += xv.x * Wb[(k0 * 4 + 0) * DO + c];
        #pragma unroll
        for (int c = 0; c < CT; ++c) acc[c] += xv.y * Wb[(k0 * 4 + 1) * DO + c];
        #pragma unroll
        for (int c = 0; c < CT; ++c) acc[c] += xv.z * Wb[(k0 * 4 + 2) * DO + c];
        #pragma unroll
        for (int c = 0; c < CT; ++c) acc[c] += xv.w * Wb[(k0 * 4 + 3) * DO + c];
    }

    float* hr = H + (size_t)node * DO + ct0;
    #pragma unroll
    for (int c4 = 0; c4 < CT / 4; ++c4) {
        float4 v;
        v.x = acc[c4 * 4 + 0]; v.y = acc[c4 * 4 + 1];
        v.z = acc[c4 * 4 + 2]; v.w = acc[c4 * 4 + 3];
        if (BIAS_RELU) {
            v.x = fmaxf(v.x, 0.0f); v.y = fmaxf(v.y, 0.0f);
            v.z = fmaxf(v.z, 0.0f); v.w = fmaxf(v.w, 0.0f);
        }
        ((float4*)hr)[c4] = v;
    }
}

// ---------------- MLP head ----------------

__global__ void __launch_bounds__(64) k_mlp(
        const float* __restrict__ O3,
        const float* __restrict__ Wf1, const float* __restrict__ bf1,
        const float* __restrict__ Wf2, const float* __restrict__ bf2,
        float* __restrict__ out, int n) {
    __shared__ float W1s[32 * 16];
    __shared__ float b1s[16];
    __shared__ float W2s[16];
    __shared__ float b2s;
    int t = threadIdx.x;
    for (int i = t; i < 32 * 16; i += 64) W1s[i] = Wf1[i];
    if (t < 16) { b1s[t] = bf1[t]; W2s[t] = Wf2[t]; }
    if (t == 0) b2s = bf2[0];
    __syncthreads();

    int node = blockIdx.x * 64 + t;
    if (node >= n) return;

    const float4* xr = (const float4*)(O3 + (size_t)node * 32);
    float4 h0 = *(const float4*)&b1s[0];
    float4 h1 = *(const float4*)&b1s[4];
    float4 h2 = *(const float4*)&b1s[8];
    float4 h3 = *(const float4*)&b1s[12];

#define MLP_STEP(xs, krow) { \
        float4 wa = *(const float4*)&W1s[(krow) * 16 + 0];  \
        float4 wb = *(const float4*)&W1s[(krow) * 16 + 4];  \
        float4 wc = *(const float4*)&W1s[(krow) * 16 + 8];  \
        float4 wd = *(const float4*)&W1s[(krow) * 16 + 12]; \
        h0.x += (xs) * wa.x; h0.y += (xs) * wa.y; h0.z += (xs) * wa.z; h0.w += (xs) * wa.w; \
        h1.x += (xs) * wb.x; h1.y += (xs) * wb.y; h1.z += (xs) * wb.z; h1.w += (xs) * wb.w; \
        h2.x += (xs) * wc.x; h2.y += (xs) * wc.y; h2.z += (xs) * wc.z; h2.w += (xs) * wc.w; \
        h3.x += (xs) * wd.x; h3.y += (xs) * wd.y; h3.z += (xs) * wd.z; h3.w += (xs) * wd.w; }

    #pragma unroll
    for (int k4 = 0; k4 < 8; ++k4) {
        float4 xv = xr[k4];
        MLP_STEP(xv.x, k4 * 4 + 0)
        MLP_STEP(xv.y, k4 * 4 + 1)
        MLP_STEP(xv.z, k4 * 4 + 2)
        MLP_STEP(xv.w, k4 * 4 + 3)
    }
#undef MLP_STEP

    float4 va = *(const float4*)&W2s[0];
    float4 vb = *(const float4*)&W2s[4];
    float4 vc = *(const float4*)&W2s[8];
    float4 vd = *(const float4*)&W2s[12];
    float acc = b2s
        + fmaxf(h0.x, 0.0f) * va.x + fmaxf(h0.y, 0.0f) * va.y
        + fmaxf(h0.z, 0.0f) * va.z + fmaxf(h0.w, 0.0f) * va.w
        + fmaxf(h1.x, 0.0f) * vb.x + fmaxf(h1.y, 0.0f) * vb.y
        + fmaxf(h1.z, 0.0f) * vb.z + fmaxf(h1.w, 0.0f) * vb.w
        + fmaxf(h2.x, 0.0f) * vc.x + fmaxf(h2.y, 0.0f) * vc.y
        + fmaxf(h2.z, 0.0f) * vc.z + fmaxf(h2.w, 0.0f) * vc.w
        + fmaxf(h3.x, 0.0f) * vd.x + fmaxf(h3.y, 0.0f) * vd.y
        + fmaxf(h3.z, 0.0f) * vd.z + fmaxf(h3.w, 0.0f) * vd.w;
    out[node] = 1.0f / (1.0f + expf(-acc));
}

// ---------------- launch ----------------

extern "C" void kernel_launch(void* const* d_in, const int* in_sizes, int n_in,
                              void* d_out, int out_size, void* d_ws, size_t ws_size,
                              hipStream_t stream) {
    const float* x   = (const float*)d_in[0];
    const int*   ei  = (const int*)d_in[1];
    const float* W1  = (const float*)d_in[2];
    const float* b1  = (const float*)d_in[3];
    const float* W2  = (const float*)d_in[4];
    const float* b2  = (const float*)d_in[5];
    const float* W3  = (const float*)d_in[6];
    const float* b3  = (const float*)d_in[7];
    const float* Wf1 = (const float*)d_in[8];
    const float* bf1 = (const float*)d_in[9];
    const float* Wf2 = (const float*)d_in[10];
    const float* bf2 = (const float*)d_in[11];
    float* out = (float*)d_out;

    const int N = N_NODES, E = N_EDGES;
    const int* src = ei;
    const int* dst = ei + E;

    char* w = (char*)d_ws;
    float* dinv    = (float*)w;                     w += (size_t)N * 4;
    int*   degc    = (int*)w;                       w += (size_t)N * 4;
    int*   row_ptr = (int*)w;                       w += (size_t)(N + 4) * 4;
    int*   cursor  = (int*)w;                       w += (size_t)N * 4;
    int*   bsum    = (int*)w;                       w += (size_t)256 * 4;
    int2*  csr_ew  = (int2*)w;                      w += (size_t)E * 8;
    float* bufA    = (float*)w;                     w += (size_t)N * 64 * 4;
    float* bufB    = (float*)w;                                              // N*128

    const int B   = 256;
    const int NB  = (N + B - 1) / B;        // 196
    const int NBX = 200;                    // multiple of 8 (XCD count)

    // ---- CSR build ----
    k_zero     <<<NB, B, 0, stream>>>(degc, N);
    k_count    <<<(E + B - 1) / B, B, 0, stream>>>(dst, degc, E);
    k_blocksum <<<NB, B, 0, stream>>>(degc, bsum, N);
    k_scanbsum <<<1, B, 0, stream>>>(bsum, NB);
    k_rowptr   <<<NB, B, 0, stream>>>(degc, bsum, row_ptr, cursor, dinv, N);
    k_fill     <<<(E + B - 1) / B, B, 0, stream>>>(src, dst, dinv, cursor, csr_ew, E);

    // ---- layer 1: aggregate x at 44 dims, then GEMM 44->128 (+b1, relu) ----
    k_agg<11, false><<<(N * 11 + B - 1) / B, B, 0, stream>>>(
        x, dinv, row_ptr, csr_ew, nullptr, bufA, N);
    k_gemm<44, 128, 16, true><<<dim3(NBX, 8), B, 0, stream>>>(bufA, W1, b1, bufB, N);

    // ---- layer 2: GEMM 128->64, aggregate at 64 (+b2, relu) ----
    k_gemm<128, 64, 16, false><<<dim3(NBX, 4), B, 0, stream>>>(bufB, W2, nullptr, bufA, N);
    k_agg<16, true><<<(N * 16 + B - 1) / B, B, 0, stream>>>(
        bufA, dinv, row_ptr, csr_ew, b2, bufB, N);

    // ---- layer 3: GEMM 64->32, aggregate at 32 (+b3, relu) ----
    k_gemm<64, 32, 8, false><<<dim3(NBX, 4), B, 0, stream>>>(bufB, W3, nullptr, bufA, N);
    k_agg<8, true><<<(N * 8 + B - 1) / B, B, 0, stream>>>(
        bufA, dinv, row_ptr, csr_ew, b3, bufB, N);

    // ---- MLP head ----
    k_mlp<<<(N + 63) / 64, 64, 0, stream>>>(bufB, Wf1, bf1, Wf2, bf2, out, N);
}